// Round 20
// baseline (351.099 us; speedup 1.0000x reference)
//
#include <hip/hip_runtime.h>
#include <hip/hip_bf16.h>
#include <math.h>

#define BB 64
#define SS 196
#define DD 768
#define EE 4
#define KKE 2
#define THH 196
#define MHH 3072
#define N1 (BB*SS*DD)
#define MM (BB*SS)
#define PP 256   // padded S/TH for token-mix GEMMs

typedef __bf16 bf16x8 __attribute__((ext_vector_type(8)));
typedef float f32x4 __attribute__((ext_vector_type(4)));

// tanh-form gelu via HW exp; |err| vs exact erf-gelu ~1e-3, far under bf16 rounding of H.
__device__ __forceinline__ float gelu_act(float x){
    float y = 1.5957691216057308f*(x + 0.044715f*x*x*x);  // 2*sqrt(2/pi)*(x+0.044715x^3)
    float e = __expf(y);
    float t = 1.f - 2.f/(e+1.f);
    return 0.5f*x*(1.f+t);
}

// ---- async global->LDS, 16B per lane; lds base must be wave-uniform ----
#define GLD16(ldsp, gp) \
    __builtin_amdgcn_global_load_lds((__attribute__((address_space(1))) void*)(gp), \
                                     (__attribute__((address_space(3))) void*)(ldsp), 16, 0, 0)

// ---------------- LN over last dim -> bf16 out, save mu/rsig ----------------
__global__ __launch_bounds__(256) void ln_bf16_kernel(const float* __restrict__ x,
                                                      const float* __restrict__ g,
                                                      const float* __restrict__ b,
                                                      __hip_bfloat16* __restrict__ out,
                                                      float* __restrict__ muo,
                                                      float* __restrict__ rso){
    int row = blockIdx.x;
    int tid = threadIdx.x;
    const float* xr = x + (size_t)row * DD;
    float v0 = xr[tid], v1 = xr[tid+256], v2 = xr[tid+512];
    float s = v0+v1+v2, ss = v0*v0+v1*v1+v2*v2;
    __shared__ float sh[10];
    int lane = tid & 63, wid = tid >> 6;
    #pragma unroll
    for (int o=32;o>0;o>>=1){ s += __shfl_down(s,o); ss += __shfl_down(ss,o); }
    if (lane==0){ sh[wid]=s; sh[4+wid]=ss; }
    __syncthreads();
    if (tid==0){
        float S1=sh[0]+sh[1]+sh[2]+sh[3], S2=sh[4]+sh[5]+sh[6]+sh[7];
        float mu = S1/DD; float var = S2/DD - mu*mu;
        float rs = rsqrtf(var + 1e-6f);
        sh[8]=mu; sh[9]=rs;
        muo[row]=mu; rso[row]=rs;
    }
    __syncthreads();
    float mu=sh[8], rs=sh[9];
    __hip_bfloat16* orow = out + (size_t)row*DD;
    orow[tid]     = __float2bfloat16((v0-mu)*rs*g[tid]     + b[tid]);
    orow[tid+256] = __float2bfloat16((v1-mu)*rs*g[tid+256] + b[tid+256]);
    orow[tid+512] = __float2bfloat16((v2-mu)*rs*g[tid+512] + b[tid+512]);
}

// ---------------- fp32 transpose -> bf16: dst[c][r] = src[r][c] (exact dims) ----------------
__global__ __launch_bounds__(256) void transpose_bf16_kernel(const float* __restrict__ src,
                                                             __hip_bfloat16* __restrict__ dst,
                                                             int R, int C){
    __shared__ float t[32][33];
    int c0 = blockIdx.x*32, r0 = blockIdx.y*32;
    int tx = threadIdx.x & 31, ty = threadIdx.x >> 5;
    #pragma unroll
    for (int rr = ty; rr < 32; rr += 8)
        t[rr][tx] = src[(size_t)(r0+rr)*C + c0 + tx];
    __syncthreads();
    #pragma unroll
    for (int cc = ty; cc < 32; cc += 8)
        dst[(size_t)(c0+cc)*R + r0 + tx] = __float2bfloat16(t[tx][cc]);
}

// ---------------- fp32 [R][C] -> bf16 transposed+padded [P][P]; z = expert ----------------
__global__ __launch_bounds__(256) void transpose_pad_w_kernel(const float* __restrict__ src0,
                                                              __hip_bfloat16* __restrict__ dst0,
                                                              int R, int C){
    const float* src = src0 + (size_t)blockIdx.z*R*C;
    __hip_bfloat16* dst = dst0 + (size_t)blockIdx.z*PP*PP;
    __shared__ float t[32][33];
    int c0 = blockIdx.x*32, r0 = blockIdx.y*32;
    int tx = threadIdx.x & 31, ty = threadIdx.x >> 5;
    #pragma unroll
    for (int rr = ty; rr < 32; rr += 8)
        t[rr][tx] = (r0+rr < R && c0+tx < C) ? src[(size_t)(r0+rr)*C + c0 + tx] : 0.f;
    __syncthreads();
    #pragma unroll
    for (int cc = ty; cc < 32; cc += 8)
        dst[(size_t)(c0+cc)*PP + r0 + tx] = __float2bfloat16(t[tx][cc]);
}

// ---------------- nbf [64][196][768] -> nTp [64][768][256] (transpose + zero-pad s) ----------------
__global__ __launch_bounds__(256) void transpose_pad_n_kernel(const __hip_bfloat16* __restrict__ src,
                                                              __hip_bfloat16* __restrict__ dst){
    int b = blockIdx.z;
    __shared__ __hip_bfloat16 t[64][66];
    int d0 = blockIdx.x*64, s0 = blockIdx.y*64;
    int lane = threadIdx.x & 63, q = threadIdx.x >> 6;
    for (int i=q; i<64; i+=4){
        int s = s0+i;
        t[i][lane] = (s < SS) ? src[((size_t)b*SS + s)*DD + d0 + lane]
                              : __float2bfloat16(0.f);
    }
    __syncthreads();
    for (int i=q; i<64; i+=4){
        int d = d0+i;
        dst[((size_t)b*DD + d)*PP + s0 + lane] = t[lane][i];
    }
}

// ---------------- meanvec: mv[b][d] = g1[d]*mean_s((x-mu)*rs) + b1[d], exact fp32 ----------------
__global__ __launch_bounds__(384) void meanvec_kernel(const float* __restrict__ x,
                                                      const float* __restrict__ mu,
                                                      const float* __restrict__ rs,
                                                      const float* __restrict__ g1,
                                                      const float* __restrict__ b1,
                                                      float* __restrict__ mv){
    int b = blockIdx.y, d = blockIdx.x*384 + threadIdx.x;
    __shared__ float smu[SS], srs[SS];
    for (int s=threadIdx.x; s<SS; s+=384){ smu[s]=mu[b*SS+s]; srs[s]=rs[b*SS+s]; }
    __syncthreads();
    const float* base = x + (size_t)b*SS*DD + d;
    float a0=0.f, a1=0.f;
    for (int s=0;s<SS;s+=2){
        a0 += (base[(size_t)s*DD]     - smu[s])  * srs[s];
        a1 += (base[(size_t)(s+1)*DD] - smu[s+1])* srs[s+1];
    }
    mv[(size_t)b*DD + d] = g1[d]*((a0+a1)/(float)SS) + b1[d];
}

// ---------------- logits + softmax + top-2 (one wave per batch) ----------------
__global__ __launch_bounds__(64) void logits_kernel(const float* __restrict__ mv,
                                                    const float* __restrict__ Wg,
                                                    const float* __restrict__ bg,
                                                    float* __restrict__ combine,
                                                    float* __restrict__ probs,
                                                    int* __restrict__ topi,
                                                    float* __restrict__ topw){
    int b = blockIdx.x, lane = threadIdx.x;
    float pl[EE] = {0.f,0.f,0.f,0.f};
    #pragma unroll
    for (int i=0;i<DD/64;++i){
        int d = lane + i*64;
        float m = mv[(size_t)b*DD + d];
        #pragma unroll
        for (int e=0;e<EE;++e) pl[e] += m * Wg[d*EE + e];
    }
    #pragma unroll
    for (int e=0;e<EE;++e){
        #pragma unroll
        for (int o=32;o>0;o>>=1) pl[e] += __shfl_down(pl[e], o);
    }
    if (lane==0){
        float lg[EE];
        for (int e=0;e<EE;++e) lg[e] = pl[e] + bg[e];
        float mx = lg[0];
        for (int e=1;e<EE;++e) mx = fmaxf(mx, lg[e]);
        float p[EE]; float sum=0.f;
        for (int e=0;e<EE;++e){ p[e]=expf(lg[e]-mx); sum+=p[e]; }
        for (int e=0;e<EE;++e) p[e] /= sum;
        int i0=0; for (int e=1;e<EE;++e) if (p[e]>p[i0]) i0=e;
        int i1=-1;
        for (int e=0;e<EE;++e){ if (e==i0) continue; if (i1<0 || p[e]>p[i1]) i1=e; }
        float v0=p[i0], v1=p[i1], rsum=v0+v1;
        float w0=v0/rsum, w1=v1/rsum;
        for (int e=0;e<EE;++e){ probs[b*EE+e]=p[e]; combine[b*EE+e]=0.f; }
        combine[b*EE+i0]=w0; combine[b*EE+i1]=w1;
        topi[b*KKE]=i0; topi[b*KKE+1]=i1;
        topw[b*KKE]=w0; topw[b*KKE+1]=w1;
    }
}

// ---------------- aux loss ----------------
__global__ __launch_bounds__(256) void aux_kernel(const float* __restrict__ combine,
                                                  const float* __restrict__ probs,
                                                  float* __restrict__ aux_out){
    int tid = threadIdx.x; int e = tid>>6, b = tid&63;
    float m = combine[b*EE+e] > 0.f ? 1.f : 0.f;
    float p = probs[b*EE+e];
    #pragma unroll
    for (int o=32;o>0;o>>=1){ m += __shfl_down(m,o); p += __shfl_down(p,o); }
    __shared__ float sh[EE];
    if ((tid&63)==0) sh[e] = (m/(float)BB)*(p/(float)BB);
    __syncthreads();
    if (tid==0) aux_out[0] = (float)EE * (sh[0]+sh[1]+sh[2]+sh[3]);
}

// ---------------- tok GEMM1: htok[be][768][256] = gelu(nTp[b] @ w1tp[e]^T + b1[e]) ----------------
// Epilogue LDS-bounce: coalesced 16B stores (avoid write-allocate refetch of htok).
__global__ __launch_bounds__(256) void tok_gemm1_kernel(
    const __hip_bfloat16* __restrict__ nTp,   // [64][768][256]
    const __hip_bfloat16* __restrict__ w1tp,  // [4][256][256]
    const float* __restrict__ b1,             // [4][196]
    const int* __restrict__ topi,
    __hip_bfloat16* __restrict__ htok)        // [128][768][256]
{
    __shared__ __hip_bfloat16 smem[128*64*2];   // As | Bs; reused as Ht[128][128]
    __hip_bfloat16* As = smem;
    __hip_bfloat16* Bs = smem + 128*64;
    int tid=threadIdx.x, lane=tid&63, w=tid>>6;
    int wm=w>>1, wn=w&1, l15=lane&15, l4=lane>>4;
    int be = blockIdx.z, b = be>>1;
    int e = __builtin_amdgcn_readfirstlane(topi[b*KKE + (be&1)]);
    int m0 = blockIdx.y*128, n0 = blockIdx.x*128;
    const __hip_bfloat16* A  = nTp  + ((size_t)b*DD + m0)*PP;
    const __hip_bfloat16* Bt = w1tp + ((size_t)e*PP + n0)*PP;
    f32x4 acc[4][4];
    #pragma unroll
    for (int mi=0;mi<4;++mi)
        #pragma unroll
        for (int ni=0;ni<4;++ni) acc[mi][ni] = (f32x4){0.f,0.f,0.f,0.f};

    int srow = w*32 + (lane>>3), sc = lane&7;
    int soff = srow*64 + ((sc ^ (srow&7))<<3);
    const __hip_bfloat16* Ap = A + (size_t)srow*PP + sc*8;
    const __hip_bfloat16* Bp = Bt + (size_t)srow*PP + sc*8;
    bf16x8 va[4], vb[4];
    #pragma unroll
    for (int i=0;i<4;++i){
        va[i] = *reinterpret_cast<const bf16x8*>(Ap + (size_t)i*8*PP);
        vb[i] = *reinterpret_cast<const bf16x8*>(Bp + (size_t)i*8*PP);
    }
    for (int k0=0; k0<PP; k0+=64){
        __syncthreads();
        #pragma unroll
        for (int i=0;i<4;++i){
            *reinterpret_cast<bf16x8*>(&As[soff + i*8*64]) = va[i];
            *reinterpret_cast<bf16x8*>(&Bs[soff + i*8*64]) = vb[i];
        }
        __syncthreads();
        if (k0+64 < PP){
            #pragma unroll
            for (int i=0;i<4;++i){
                va[i] = *reinterpret_cast<const bf16x8*>(Ap + (size_t)i*8*PP + (k0+64));
                vb[i] = *reinterpret_cast<const bf16x8*>(Bp + (size_t)i*8*PP + (k0+64));
            }
        }
        #pragma unroll
        for (int kk=0;kk<2;++kk){
            bf16x8 af[4], bfr[4];
            #pragma unroll
            for (int mi=0;mi<4;++mi){
                int r = wm*64 + mi*16 + l15, kc = kk*4 + l4;
                af[mi] = *reinterpret_cast<const bf16x8*>(&As[r*64 + ((kc ^ (r&7))<<3)]);
            }
            #pragma unroll
            for (int ni=0;ni<4;++ni){
                int r = wn*64 + ni*16 + l15, kc = kk*4 + l4;
                bfr[ni] = *reinterpret_cast<const bf16x8*>(&Bs[r*64 + ((kc ^ (r&7))<<3)]);
            }
            #pragma unroll
            for (int mi=0;mi<4;++mi)
                #pragma unroll
                for (int ni=0;ni<4;++ni)
                    acc[mi][ni] = __builtin_amdgcn_mfma_f32_16x16x32_bf16(af[mi], bfr[ni], acc[mi][ni], 0, 0, 0);
        }
    }
    // epilogue: gelu -> Ht in LDS -> coalesced 16B stores
    __syncthreads();
    __hip_bfloat16* Ht = smem;   // [128][128]
    #pragma unroll
    for (int mi=0;mi<4;++mi){
        #pragma unroll
        for (int ni=0;ni<4;++ni){
            int colL = wn*64 + ni*16 + l15;
            int col = n0 + colL;
            float bv = (col < THH) ? b1[e*THH + col] : 0.f;
            #pragma unroll
            for (int r=0;r<4;++r){
                int rowL = wm*64 + mi*16 + l4*4 + r;
                float v = (col < THH) ? gelu_act(acc[mi][ni][r] + bv) : 0.f;
                Ht[rowL*128 + colL] = __float2bfloat16(v);
            }
        }
    }
    __syncthreads();
    for (int i = tid; i < 128*128/8; i += 256){
        int rowL = i >> 4, c8 = i & 15;
        *reinterpret_cast<bf16x8*>(&htok[((size_t)be*DD + m0 + rowL)*PP + n0 + c8*8])
            = *reinterpret_cast<const bf16x8*>(&Ht[rowL*128 + c8*8]);
    }
}

// ---------------- tok GEMM2: x1 = x + sum_k wk*(htok[b,k] @ w2tp[ek]^T + b2[ek]) ----------------
__global__ __launch_bounds__(256) void tok_gemm2_kernel(
    const __hip_bfloat16* __restrict__ htok,  // [128][768][256]
    const __hip_bfloat16* __restrict__ w2tp,  // [4][256][256]
    const float* __restrict__ b2,             // [4][196]
    const int* __restrict__ topi, const float* __restrict__ topw,
    const float* __restrict__ x, float* __restrict__ x1)
{
    __shared__ __hip_bfloat16 As[128*64];
    __shared__ __hip_bfloat16 Bs[128*64];
    int tid=threadIdx.x, lane=tid&63, w=tid>>6;
    int wm=w>>1, wn=w&1, l15=lane&15, l4=lane>>4;
    int b = blockIdx.z;
    int m0 = blockIdx.y*128, n0 = blockIdx.x*128;
    float w0 = topw[b*KKE], w1 = topw[b*KKE+1];
    f32x4 acc[4][4];
    #pragma unroll
    for (int mi=0;mi<4;++mi)
        #pragma unroll
        for (int ni=0;ni<4;++ni) acc[mi][ni] = (f32x4){0.f,0.f,0.f,0.f};

    int srow = w*32 + (lane>>3), sc = lane&7;
    int soff = srow*64 + ((sc ^ (srow&7))<<3);

    for (int pass=0; pass<2; ++pass){
        int e = __builtin_amdgcn_readfirstlane(topi[b*KKE + pass]);
        const __hip_bfloat16* Ap = htok + ((size_t)(b*KKE+pass)*DD + m0 + srow)*PP + sc*8;
        const __hip_bfloat16* Bp = w2tp + ((size_t)e*PP + n0 + srow)*PP + sc*8;
        bf16x8 va[4], vb[4];
        #pragma unroll
        for (int i=0;i<4;++i){
            va[i] = *reinterpret_cast<const bf16x8*>(Ap + (size_t)i*8*PP);
            vb[i] = *reinterpret_cast<const bf16x8*>(Bp + (size_t)i*8*PP);
        }
        for (int k0=0; k0<PP; k0+=64){
            __syncthreads();
            #pragma unroll
            for (int i=0;i<4;++i){
                *reinterpret_cast<bf16x8*>(&As[soff + i*8*64]) = va[i];
                *reinterpret_cast<bf16x8*>(&Bs[soff + i*8*64]) = vb[i];
            }
            __syncthreads();
            if (k0+64 < PP){
                #pragma unroll
                for (int i=0;i<4;++i){
                    va[i] = *reinterpret_cast<const bf16x8*>(Ap + (size_t)i*8*PP + (k0+64));
                    vb[i] = *reinterpret_cast<const bf16x8*>(Bp + (size_t)i*8*PP + (k0+64));
                }
            }
            #pragma unroll
            for (int kk=0;kk<2;++kk){
                bf16x8 af[4], bfr[4];
                #pragma unroll
                for (int mi=0;mi<4;++mi){
                    int r = wm*64 + mi*16 + l15, kc = kk*4 + l4;
                    af[mi] = *reinterpret_cast<const bf16x8*>(&As[r*64 + ((kc ^ (r&7))<<3)]);
                }
                #pragma unroll
                for (int ni=0;ni<4;++ni){
                    int r = wn*64 + ni*16 + l15, kc = kk*4 + l4;
                    bfr[ni] = *reinterpret_cast<const bf16x8*>(&Bs[r*64 + ((kc ^ (r&7))<<3)]);
                }
                #pragma unroll
                for (int mi=0;mi<4;++mi)
                    #pragma unroll
                    for (int ni=0;ni<4;++ni)
                        acc[mi][ni] = __builtin_amdgcn_mfma_f32_16x16x32_bf16(af[mi], bfr[ni], acc[mi][ni], 0, 0, 0);
            }
        }
        if (pass==0){
            float sc0 = w0 / w1;   // softmax top-2 renorm => w1 > 0
            #pragma unroll
            for (int mi=0;mi<4;++mi)
                #pragma unroll
                for (int ni=0;ni<4;++ni)
                    #pragma unroll
                    for (int r=0;r<4;++r) acc[mi][ni][r] *= sc0;
        }
    }
    int e0 = topi[b*KKE], e1 = topi[b*KKE+1];
    #pragma unroll
    for (int mi=0;mi<4;++mi){
        #pragma unroll
        for (int ni=0;ni<4;++ni){
            int col = n0 + wn*64 + ni*16 + l15;   // s index
            if (col < SS){
                float bias = w0*b2[e0*SS+col] + w1*b2[e1*SS+col];
                int rowb = m0 + wm*64 + mi*16 + l4*4;
                size_t idx = ((size_t)b*SS + col)*DD + rowb;
                f32x4 xv = *reinterpret_cast<const f32x4*>(x + idx);
                f32x4 res;
                #pragma unroll
                for (int r=0;r<4;++r) res[r] = xv[r] + w1*acc[mi][ni][r] + bias;
                *reinterpret_cast<f32x4*>(x1 + idx) = res;
            }
        }
    }
}

// ---------------- token mixing fallback (round-7 kernel) ----------------
__global__ __launch_bounds__(256) void tokenmix2_kernel(
    const __hip_bfloat16* __restrict__ nbf, const float* __restrict__ x,
    const float* __restrict__ W1, const float* __restrict__ b1,
    const float* __restrict__ W2, const float* __restrict__ b2,
    const int* __restrict__ topi, const float* __restrict__ topw,
    float* __restrict__ x1)
{
    __shared__ __hip_bfloat16 xs[SS][64];
    __shared__ __hip_bfloat16 Hs[THH][64];
    int b = blockIdx.y, d0 = blockIdx.x*64;
    int tid = threadIdx.x, lane = tid&63, w = tid>>6;
    for (int s = w; s < SS; s += 4)
        xs[s][lane] = nbf[((size_t)b*SS + s)*DD + d0 + lane];
    #pragma unroll
    for (int k=0;k<KKE;++k){
        int e = __builtin_amdgcn_readfirstlane(topi[b*KKE+k]);
        float wgt = topw[b*KKE+k];
        __syncthreads();
        const float* W1e = W1 + (size_t)e*SS*THH;
        for (int hj=0; hj<13; ++hj){
            int hb = w + 16*hj;
            if (hj < 12){
                float a0=b1[e*THH+hb], a1=b1[e*THH+hb+4], a2=b1[e*THH+hb+8], a3=b1[e*THH+hb+12];
                for (int s=0;s<SS;++s){
                    float xv = __bfloat162float(xs[s][lane]);
                    const float* wr = W1e + (size_t)s*THH + hb;
                    a0 += xv*wr[0]; a1 += xv*wr[4]; a2 += xv*wr[8]; a3 += xv*wr[12];
                }
                Hs[hb][lane]    = __float2bfloat16(gelu_act(a0));
                Hs[hb+4][lane]  = __float2bfloat16(gelu_act(a1));
                Hs[hb+8][lane]  = __float2bfloat16(gelu_act(a2));
                Hs[hb+12][lane] = __float2bfloat16(gelu_act(a3));
            } else {
                float a0=b1[e*THH+hb];
                for (int s=0;s<SS;++s)
                    a0 += __bfloat162float(xs[s][lane]) * W1e[(size_t)s*THH + hb];
                Hs[hb][lane] = __float2bfloat16(gelu_act(a0));
            }
        }
        __syncthreads();
        const float* W2e = W2 + (size_t)e*THH*SS;
        for (int sj=0; sj<13; ++sj){
            int sb = w + 16*sj;
            if (sj < 12){
                float o0=b2[e*SS+sb], o1=b2[e*SS+sb+4], o2=b2[e*SS+sb+8], o3=b2[e*SS+sb+12];
                for (int h=0;h<THH;++h){
                    float hv = __bfloat162float(Hs[h][lane]);
                    const float* wr = W2e + (size_t)h*SS + sb;
                    o0 += hv*wr[0]; o1 += hv*wr[4]; o2 += hv*wr[8]; o3 += hv*wr[12];
                }
                float ov[4] = {o0,o1,o2,o3};
                #pragma unroll
                for (int u=0;u<4;++u){
                    size_t idx = ((size_t)b*SS + sb + 4*u)*DD + d0 + lane;
                    float val = wgt*ov[u];
                    if (k==0) x1[idx] = x[idx] + val; else x1[idx] += val;
                }
            } else {
                float o0=b2[e*SS+sb];
                for (int h=0;h<THH;++h)
                    o0 += __bfloat162float(Hs[h][lane]) * W2e[(size_t)h*SS + sb];
                size_t idx = ((size_t)b*SS + sb)*DD + d0 + lane;
                float val = wgt*o0;
                if (k==0) x1[idx] = x[idx] + val; else x1[idx] += val;
            }
        }
    }
}

// ---------------- tiled MFMA GEMM, B^T input (channel MLP GEMM1) ----------------
// BM=128, BN=128. Reg-prefetch staging + XOR-swizzled LDS + M-grouped XCD mapping.
// LDS-bounce epilogue for coalesced bf16 stores.
template<int KDIM, int NBLK, int MB>
__global__ __launch_bounds__(256) void gemm_bt_kernel(
    const __hip_bfloat16* __restrict__ A,
    const __hip_bfloat16* __restrict__ Bt,
    const float* __restrict__ bias,
    __hip_bfloat16* __restrict__ Hout,
    int Ntot)
{
    constexpr int BN = 128;
    int id = blockIdx.x;
    int r8 = id & 7, t = id >> 3;
    int qm = t / NBLK, n = t - qm*NBLK;
    int m  = qm*8 + r8;
    if (m >= MB) return;
    int m0 = m*128, n0 = n*BN;

    __shared__ __hip_bfloat16 smem[128*64 + BN*64];  // As | Bs; reused as Ht[128][BN]
    __hip_bfloat16* As = smem;
    __hip_bfloat16* Bs = smem + 128*64;
    int tid = threadIdx.x, lane = tid&63, w = tid>>6;
    int wm = w>>1, wn = w&1;
    int l15 = lane&15, l4 = lane>>4;
    f32x4 acc[4][4];
    #pragma unroll
    for (int mi=0;mi<4;++mi)
        #pragma unroll
        for (int ni=0;ni<4;++ni) acc[mi][ni] = (f32x4){0.f,0.f,0.f,0.f};

    int r0 = tid>>3;                 // 0..31
    int sc = tid&7;
    int soff = r0*64 + ((sc ^ (r0&7))<<3);
    const __hip_bfloat16* Ap = A  + (size_t)(m0+r0)*KDIM + sc*8;
    const __hip_bfloat16* Bp = Bt + (size_t)(n0+r0)*KDIM + sc*8;

    bf16x8 va[4], vb[4];
    #pragma unroll
    for (int i=0;i<4;++i){
        va[i] = *reinterpret_cast<const bf16x8*>(Ap + (size_t)i*32*KDIM);
        vb[i] = *reinterpret_cast<const bf16x8*>(Bp + (size_t)i*32*KDIM);
    }
    for (int k0=0; k0<KDIM; k0+=64){
        __syncthreads();
        #pragma unroll
        for (int i=0;i<4;++i){
            *reinterpret_cast<bf16x8*>(&As[soff + i*32*64]) = va[i];
            *reinterpret_cast<bf16x8*>(&Bs[soff + i*32*64]) = vb[i];
        }
        __syncthreads();
        if (k0+64 < KDIM){
            #pragma unroll
            for (int i=0;i<4;++i){
                va[i] = *reinterpret_cast<const bf16x8*>(Ap + (size_t)i*32*KDIM + (k0+64));
                vb[i] = *reinterpret_cast<const bf16x8*>(Bp + (size_t)i*32*KDIM + (k0+64));
            }
        }
        #pragma unroll
        for (int kk=0;kk<2;++kk){
            bf16x8 af[4], bfr[4];
            #pragma unroll
            for (int mi=0;mi<4;++mi){
                int r = wm*64 + mi*16 + l15;
                int kc = kk*4 + l4;
                af[mi] = *reinterpret_cast<const bf16x8*>(&As[r*64 + ((kc ^ (r&7))<<3)]);
            }
            #pragma unroll
            for (int ni=0;ni<4;++ni){
                int r = wn*64 + ni*16 + l15;
                int kc = kk*4 + l4;
                bfr[ni] = *reinterpret_cast<const bf16x8*>(&Bs[r*64 + ((kc ^ (r&7))<<3)]);
            }
            #pragma unroll
            for (int mi=0;mi<4;++mi)
                #pragma unroll
                for (int ni=0;ni<4;++ni)
                    acc[mi][ni] = __builtin_amdgcn_mfma_f32_16x16x32_bf16(af[mi], bfr[ni], acc[mi][ni], 0, 0, 0);
        }
    }
    // gelu -> Ht in LDS -> coalesced 16B stores (no write-allocate refetch)
    __syncthreads();
    __hip_bfloat16* Ht = smem;   // [128][BN]
    #pragma unroll
    for (int mi=0;mi<4;++mi){
        #pragma unroll
        for (int ni=0;ni<4;++ni){
            int colL = wn*64 + ni*16 + l15;
            float bv = bias[n0 + colL];
            #pragma unroll
            for (int r=0;r<4;++r){
                int rowL = wm*64 + mi*16 + l4*4 + r;
                Ht[rowL*BN + colL] = __float2bfloat16(gelu_act(acc[mi][ni][r] + bv));
            }
        }
    }
    __syncthreads();
    for (int i = tid; i < 128*BN/8; i += 256){
        int rowL = i / (BN/8), c8 = i % (BN/8);
        *reinterpret_cast<bf16x8*>(&Hout[(size_t)(m0+rowL)*Ntot + n0 + c8*8])
            = *reinterpret_cast<const bf16x8*>(&Ht[rowL*BN + c8*8]);
    }
}

// ---------------- MLP GEMM2: T3 minimum 2-phase pipeline (dbuf global_load_lds) ----------------
// BM=128, BN=64, BK=64. Single barrier per k-step; next-tile loads issued before
// compute, drained by the end-of-iter barrier (compiler emits vmcnt(0) there).
// Linear LDS dest + pre-swizzled global source + swizzled read (rule #21).
template<int KDIM, int NBLK, int MB>
__global__ __launch_bounds__(256) void gemm2_pipe_kernel(
    const __hip_bfloat16* __restrict__ A,    // [M][KDIM] (Hmlp)
    const __hip_bfloat16* __restrict__ Bt,   // [N][KDIM] (w2t)
    const float* __restrict__ bias,
    float* __restrict__ Cio,
    int Ntot)
{
    constexpr int BN = 64;
    int id = blockIdx.x;
    int r8 = id & 7, t = id >> 3;
    int qm = t / NBLK, n = t - qm*NBLK;
    int m  = qm*8 + r8;
    if (m >= MB) return;
    int m0 = m*128, n0 = n*BN;

    __shared__ __hip_bfloat16 As[2][128*64];
    __shared__ __hip_bfloat16 Bs[2][BN*64];
    int tid = threadIdx.x, lane = tid&63, w = tid>>6;
    int wm = w>>1, wn = w&1;
    int l15 = lane&15, l4 = lane>>4;
    f32x4 acc[4][2];
    #pragma unroll
    for (int mi=0;mi<4;++mi){ acc[mi][0]=(f32x4){0,0,0,0}; acc[mi][1]=(f32x4){0,0,0,0}; }

    const __hip_bfloat16* Ag = A  + (size_t)m0*KDIM;
    const __hip_bfloat16* Bg = Bt + (size_t)n0*KDIM;

    // stage one k-tile into buffer p: A 1024 chunks (4/thr), B 512 chunks (2/thr).
    // LDS chunk cg=(row,c) receives global col (c ^ (row&7)); read uses kc^(r&7).
    auto stage = [&](int p, int k0){
        #pragma unroll
        for (int i=0;i<4;++i){
            int cb = i*256 + w*64;           // wave-uniform chunk base
            int cg = cb + lane;
            int row = cg>>3;
            int col = ((cg&7) ^ (row&7))*8;  // pre-swizzled source column
            GLD16(&As[p][cb*8], Ag + (size_t)row*KDIM + k0 + col);
        }
        #pragma unroll
        for (int i=0;i<2;++i){
            int cb = i*256 + w*64;
            int cg = cb + lane;
            int row = cg>>3;
            int col = ((cg&7) ^ (row&7))*8;
            GLD16(&Bs[p][cb*8], Bg + (size_t)row*KDIM + k0 + col);
        }
    };

    stage(0, 0);
    __syncthreads();          // drain prologue loads
    int cur = 0;
    for (int k0=0; k0<KDIM; k0+=64){
        if (k0+64 < KDIM) stage(cur^1, k0+64);   // async loads overlap MFMA below
        #pragma unroll
        for (int kk=0;kk<2;++kk){
            bf16x8 af[4], bfr[2];
            #pragma unroll
            for (int mi=0;mi<4;++mi){
                int r = wm*64 + mi*16 + l15;
                int kc = kk*4 + l4;
                af[mi] = *reinterpret_cast<const bf16x8*>(&As[cur][r*64 + ((kc ^ (r&7))<<3)]);
            }
            #pragma unroll
            for (int ni=0;ni<2;++ni){
                int r = wn*32 + ni*16 + l15;
                int kc = kk*4 + l4;
                bfr[ni] = *reinterpret_cast<const bf16x8*>(&Bs[cur][r*64 + ((kc ^ (r&7))<<3)]);
            }
            #pragma unroll
            for (int mi=0;mi<4;++mi){
                acc[mi][0] = __builtin_amdgcn_mfma_f32_16x16x32_bf16(af[mi], bfr[0], acc[mi][0], 0, 0, 0);
                acc[mi][1] = __builtin_amdgcn_mfma_f32_16x16x32_bf16(af[mi], bfr[1], acc[mi][1], 0, 0, 0);
            }
        }
        __syncthreads();      // drains staged loads + guards buffer reuse
        cur ^= 1;
    }
    #pragma unroll
    for (int mi=0;mi<4;++mi){
        #pragma unroll
        for (int ni=0;ni<2;++ni){
            int col = n0 + wn*32 + ni*16 + l15;
            float bv = bias[col];
            #pragma unroll
            for (int r=0;r<4;++r){
                int row = m0 + wm*64 + mi*16 + l4*4 + r;
                Cio[(size_t)row*Ntot + col] += acc[mi][ni][r] + bv;
            }
        }
    }
}

// ---------------- fallback fused MLP (validated round 6) ----------------
__global__ __launch_bounds__(512, 4) void mlp_mfma_kernel(
    const __hip_bfloat16* __restrict__ n2b,
    const __hip_bfloat16* __restrict__ w1t,
    const float* __restrict__ bm1,
    const __hip_bfloat16* __restrict__ w2t,
    const float* __restrict__ bm2,
    float* __restrict__ io)
{
    __shared__ __align__(16) __hip_bfloat16 Ht[32*64];
    int tid = threadIdx.x;
    int wid = tid >> 6, lane = tid & 63;
    int wm = wid >> 2, wn = wid & 3;
    int l15 = lane & 15, l4 = lane >> 4;
    int m0 = blockIdx.x * 32;
    f32x4 acc[12];
    #pragma unroll
    for (int f=0; f<12; ++f) acc[f] = (f32x4){0.f,0.f,0.f,0.f};
    const __hip_bfloat16* aptr = n2b + (size_t)(m0 + wm*16 + l15)*DD + l4*8;
    for (int hc = 0; hc < MHH; hc += 64) {
        f32x4 h = (f32x4){0.f,0.f,0.f,0.f};
        const __hip_bfloat16* bptr = w1t + (size_t)(hc + wn*16 + l15)*DD + l4*8;
        #pragma unroll 4
        for (int ks = 0; ks < DD; ks += 32) {
            bf16x8 a = *reinterpret_cast<const bf16x8*>(aptr + ks);
            bf16x8 bb = *reinterpret_cast<const bf16x8*>(bptr + ks);
            h = __builtin_amdgcn_mfma_f32_16x16x32_bf16(a, bb, h, 0, 0, 0);
        }
        float bv = bm1[hc + wn*16 + l15];
        __syncthreads();
        {
            int col = wn*16 + l15;
            int chunk = col >> 3, inner = col & 7;
            #pragma unroll
            for (int r=0; r<4; ++r) {
                int row = wm*16 + l4*4 + r;
                float v = gelu_act(h[r] + bv);
                Ht[row*64 + ((chunk ^ (row&7))<<3) + inner] = __float2bfloat16(v);
            }
        }
        __syncthreads();
        #pragma unroll
        for (int kk = 0; kk < 2; ++kk) {
            int arow = wm*16 + l15;
            int ach = (kk*32 + l4*8) >> 3;
            bf16x8 aH = *reinterpret_cast<const bf16x8*>(&Ht[arow*64 + ((ach ^ (arow&7))<<3)]);
            const __hip_bfloat16* b2p = w2t + (size_t)(wn*192 + l15)*MHH + hc + kk*32 + l4*8;
            #pragma unroll
            for (int f=0; f<12; ++f) {
                bf16x8 bb = *reinterpret_cast<const bf16x8*>(b2p + (size_t)f*16*MHH);
                acc[f] = __builtin_amdgcn_mfma_f32_16x16x32_bf16(aH, bb, acc[f], 0, 0, 0);
            }
        }
    }
    #pragma unroll
    for (int f=0; f<12; ++f) {
        int col = wn*192 + f*16 + l15;
        float b2v = bm2[col];
        #pragma unroll
        for (int r=0; r<4; ++r) {
            size_t idx = (size_t)(m0 + wm*16 + l4*4 + r)*DD + col;
            io[idx] += acc[f][r] + b2v;
        }
    }
}

extern "C" void kernel_launch(void* const* d_in, const int* in_sizes, int n_in,
                              void* d_out, int out_size, void* d_ws, size_t ws_size,
                              hipStream_t stream) {
    const float* x    = (const float*)d_in[0];
    const float* g1   = (const float*)d_in[1];
    const float* be1  = (const float*)d_in[2];
    const float* Wg   = (const float*)d_in[3];
    const float* bg   = (const float*)d_in[4];
    const float* W1   = (const float*)d_in[5];
    const float* b1e  = (const float*)d_in[6];
    const float* W2   = (const float*)d_in[7];
    const float* b2e  = (const float*)d_in[8];
    const float* g2   = (const float*)d_in[9];
    const float* be2  = (const float*)d_in[10];
    const float* Wm1  = (const float*)d_in[11];
    const float* bm1  = (const float*)d_in[12];
    const float* Wm2  = (const float*)d_in[13];
    const float* bm2  = (const float*)d_in[14];

    float* out = (float*)d_out;
    char* w = (char*)d_ws;

    // ---- ws layout (with aliasing): ----
    const size_t OFF_W1T  = 19267584;                 // nbf: 12544*768*2
    const size_t OFF_W2T  = OFF_W1T + 4718592;        // w1t (mlp)
    const size_t OFF_W1TP = OFF_W2T + 4718592;        // w2t (mlp)   -> 28,704,768
    const size_t OFF_W2TP = OFF_W1TP + (size_t)EE*PP*PP*2;   // +524,288
    const size_t OFF_REG  = OFF_W2TP + (size_t)EE*PP*PP*2;   // 29,753,344
    const size_t NTP_B    = (size_t)BB*DD*PP*2;       // 25,165,824
    const size_t HTOK_B   = (size_t)BB*KKE*DD*PP*2;   // 50,331,648
    const size_t HMLP_B   = (size_t)MM*MHH*2;         // 77,070,336
    const size_t REG_B    = (NTP_B + HTOK_B > HMLP_B) ? (NTP_B + HTOK_B) : HMLP_B;
    const size_t REG_END  = OFF_REG + REG_B;          // 106,823,680
    const size_t NEED     = REG_END + 400000;
    bool bigws = (ws_size >= NEED);

    __hip_bfloat16* nbf  = (__hip_bfloat16*)w;
    __hip_bfloat16* w1t  = (__hip_bfloat16*)(w + OFF_W1T);
    __hip_bfloat16* w2t  = (__hip_bfloat16*)(w + OFF_W2T);
    __hip_bfloat16* w1tp = (__hip_bfloat16*)(w + OFF_W1TP);
    __hip_bfloat16* w2tp = (__hip_bfloat16*)(w + OFF_W2TP);
    __hip_bfloat16* nTp  = (__hip_bfloat16*)(w + OFF_REG);
    __hip_bfloat16* htok = (__hip_bfloat16*)(w + OFF_REG + NTP_B);
    __hip_bfloat16* Hmlp = (__hip_bfloat16*)(w + OFF_REG);

    size_t tail = bigws ? REG_END : OFF_W1TP;
    float* muv     = (float*)(w + tail);
    float* rsigv   = muv + MM;
    float* mv      = rsigv + MM;
    float* combine = mv + (size_t)BB*DD;
    float* probs   = combine + BB*EE;
    float* topw    = probs + BB*EE;
    int*   topi    = (int*)(topw + BB*KKE);

    // 0) one-off weight transposes
    transpose_bf16_kernel<<<dim3(MHH/32, DD/32), 256, 0, stream>>>(Wm1, w1t, DD, MHH);
    transpose_bf16_kernel<<<dim3(DD/32, MHH/32), 256, 0, stream>>>(Wm2, w2t, MHH, DD);
    if (bigws){
        transpose_pad_w_kernel<<<dim3(PP/32, PP/32, EE), 256, 0, stream>>>(W1, w1tp, SS, THH);
        transpose_pad_w_kernel<<<dim3(PP/32, PP/32, EE), 256, 0, stream>>>(W2, w2tp, THH, SS);
    }
    // 1) LN1 -> nbf (bf16) + stats
    ln_bf16_kernel<<<MM, 256, 0, stream>>>(x, g1, be1, nbf, muv, rsigv);
    // 2) router (exact fp32) + aux
    meanvec_kernel<<<dim3(2, BB), 384, 0, stream>>>(x, muv, rsigv, g1, be1, mv);
    logits_kernel<<<BB, 64, 0, stream>>>(mv, Wg, bg, combine, probs, topi, topw);
    aux_kernel<<<1, 256, 0, stream>>>(combine, probs, out + N1);
    // 3) token mixing + residual -> x1 in d_out
    if (bigws){
        transpose_pad_n_kernel<<<dim3(DD/64, PP/64, BB), 256, 0, stream>>>(nbf, nTp);
        tok_gemm1_kernel<<<dim3(PP/128, DD/128, BB*KKE), 256, 0, stream>>>(nTp, w1tp, b1e, topi, htok);
        tok_gemm2_kernel<<<dim3(PP/128, DD/128, BB), 256, 0, stream>>>(htok, w2tp, b2e, topi, topw, x, out);
    } else {
        tokenmix2_kernel<<<dim3(DD/64, BB), 256, 0, stream>>>(nbf, x, W1, b1e, W2, b2e,
                                                              topi, topw, out);
    }
    // 4) LN2(x1) -> nbf
    ln_bf16_kernel<<<MM, 256, 0, stream>>>(out, g2, be2, nbf, muv, rsigv);
    // 5) channel MLP — M-grouped XCD mapping (8 * ceil(98/8)=13 qm-groups)
    if (bigws){
        // GEMM1: 128x128 tile, LDS-bounce epilogue (reg-prefetch staging)
        gemm_bt_kernel<DD, MHH/128, MM/128><<<8*13*(MHH/128), 256, 0, stream>>>(
            nbf, w1t, bm1, Hmlp, MHH);
        // GEMM2: 128x64 tile, T3 2-phase dbuf global_load_lds pipeline
        gemm2_pipe_kernel<MHH, DD/64, MM/128><<<8*13*(DD/64), 256, 0, stream>>>(
            Hmlp, w2t, bm2, out, DD);
    } else {
        mlp_mfma_kernel<<<MM/32, 512, 0, stream>>>(nbf, w1t, bm1, w2t, bm2, out);
    }
}

// Round 23
// 343.985 us; speedup vs baseline: 1.0207x; 1.0207x over previous
//
#include <hip/hip_runtime.h>
#include <hip/hip_bf16.h>
#include <math.h>

#define BB 64
#define SS 196
#define DD 768
#define EE 4
#define KKE 2
#define THH 196
#define MHH 3072
#define N1 (BB*SS*DD)
#define MM (BB*SS)
#define PP 256   // padded S/TH for token-mix GEMMs

typedef __bf16 bf16x8 __attribute__((ext_vector_type(8)));
typedef float f32x4 __attribute__((ext_vector_type(4)));

// tanh-form gelu via HW exp; |err| vs exact erf-gelu ~1e-3, far under bf16 rounding of H.
__device__ __forceinline__ float gelu_act(float x){
    float y = 1.5957691216057308f*(x + 0.044715f*x*x*x);  // 2*sqrt(2/pi)*(x+0.044715x^3)
    float e = __expf(y);
    float t = 1.f - 2.f/(e+1.f);
    return 0.5f*x*(1.f+t);
}

// ---------------- LN over last dim -> bf16 out, save mu/rsig ----------------
__global__ __launch_bounds__(256) void ln_bf16_kernel(const float* __restrict__ x,
                                                      const float* __restrict__ g,
                                                      const float* __restrict__ b,
                                                      __hip_bfloat16* __restrict__ out,
                                                      float* __restrict__ muo,
                                                      float* __restrict__ rso){
    int row = blockIdx.x;
    int tid = threadIdx.x;
    const float* xr = x + (size_t)row * DD;
    float v0 = xr[tid], v1 = xr[tid+256], v2 = xr[tid+512];
    float s = v0+v1+v2, ss = v0*v0+v1*v1+v2*v2;
    __shared__ float sh[10];
    int lane = tid & 63, wid = tid >> 6;
    #pragma unroll
    for (int o=32;o>0;o>>=1){ s += __shfl_down(s,o); ss += __shfl_down(ss,o); }
    if (lane==0){ sh[wid]=s; sh[4+wid]=ss; }
    __syncthreads();
    if (tid==0){
        float S1=sh[0]+sh[1]+sh[2]+sh[3], S2=sh[4]+sh[5]+sh[6]+sh[7];
        float mu = S1/DD; float var = S2/DD - mu*mu;
        float rs = rsqrtf(var + 1e-6f);
        sh[8]=mu; sh[9]=rs;
        muo[row]=mu; rso[row]=rs;
    }
    __syncthreads();
    float mu=sh[8], rs=sh[9];
    __hip_bfloat16* orow = out + (size_t)row*DD;
    orow[tid]     = __float2bfloat16((v0-mu)*rs*g[tid]     + b[tid]);
    orow[tid+256] = __float2bfloat16((v1-mu)*rs*g[tid+256] + b[tid+256]);
    orow[tid+512] = __float2bfloat16((v2-mu)*rs*g[tid+512] + b[tid+512]);
}

// ---------------- fp32 transpose -> bf16: dst[c][r] = src[r][c] (exact dims) ----------------
__global__ __launch_bounds__(256) void transpose_bf16_kernel(const float* __restrict__ src,
                                                             __hip_bfloat16* __restrict__ dst,
                                                             int R, int C){
    __shared__ float t[32][33];
    int c0 = blockIdx.x*32, r0 = blockIdx.y*32;
    int tx = threadIdx.x & 31, ty = threadIdx.x >> 5;
    #pragma unroll
    for (int rr = ty; rr < 32; rr += 8)
        t[rr][tx] = src[(size_t)(r0+rr)*C + c0 + tx];
    __syncthreads();
    #pragma unroll
    for (int cc = ty; cc < 32; cc += 8)
        dst[(size_t)(c0+cc)*R + r0 + tx] = __float2bfloat16(t[tx][cc]);
}

// ---------------- fp32 [R][C] -> bf16 transposed+padded [P][P]; z = expert ----------------
__global__ __launch_bounds__(256) void transpose_pad_w_kernel(const float* __restrict__ src0,
                                                              __hip_bfloat16* __restrict__ dst0,
                                                              int R, int C){
    const float* src = src0 + (size_t)blockIdx.z*R*C;
    __hip_bfloat16* dst = dst0 + (size_t)blockIdx.z*PP*PP;
    __shared__ float t[32][33];
    int c0 = blockIdx.x*32, r0 = blockIdx.y*32;
    int tx = threadIdx.x & 31, ty = threadIdx.x >> 5;
    #pragma unroll
    for (int rr = ty; rr < 32; rr += 8)
        t[rr][tx] = (r0+rr < R && c0+tx < C) ? src[(size_t)(r0+rr)*C + c0 + tx] : 0.f;
    __syncthreads();
    #pragma unroll
    for (int cc = ty; cc < 32; cc += 8)
        dst[(size_t)(c0+cc)*PP + r0 + tx] = __float2bfloat16(t[tx][cc]);
}

// ---------------- nbf [64][196][768] -> nTp [64][768][256] (transpose + zero-pad s) ----------------
__global__ __launch_bounds__(256) void transpose_pad_n_kernel(const __hip_bfloat16* __restrict__ src,
                                                              __hip_bfloat16* __restrict__ dst){
    int b = blockIdx.z;
    __shared__ __hip_bfloat16 t[64][66];
    int d0 = blockIdx.x*64, s0 = blockIdx.y*64;
    int lane = threadIdx.x & 63, q = threadIdx.x >> 6;
    for (int i=q; i<64; i+=4){
        int s = s0+i;
        t[i][lane] = (s < SS) ? src[((size_t)b*SS + s)*DD + d0 + lane]
                              : __float2bfloat16(0.f);
    }
    __syncthreads();
    for (int i=q; i<64; i+=4){
        int d = d0+i;
        dst[((size_t)b*DD + d)*PP + s0 + lane] = t[lane][i];
    }
}

// ---------------- meanvec: mv[b][d] = g1[d]*mean_s((x-mu)*rs) + b1[d], exact fp32 ----------------
__global__ __launch_bounds__(384) void meanvec_kernel(const float* __restrict__ x,
                                                      const float* __restrict__ mu,
                                                      const float* __restrict__ rs,
                                                      const float* __restrict__ g1,
                                                      const float* __restrict__ b1,
                                                      float* __restrict__ mv){
    int b = blockIdx.y, d = blockIdx.x*384 + threadIdx.x;
    __shared__ float smu[SS], srs[SS];
    for (int s=threadIdx.x; s<SS; s+=384){ smu[s]=mu[b*SS+s]; srs[s]=rs[b*SS+s]; }
    __syncthreads();
    const float* base = x + (size_t)b*SS*DD + d;
    float a0=0.f, a1=0.f;
    for (int s=0;s<SS;s+=2){
        a0 += (base[(size_t)s*DD]     - smu[s])  * srs[s];
        a1 += (base[(size_t)(s+1)*DD] - smu[s+1])* srs[s+1];
    }
    mv[(size_t)b*DD + d] = g1[d]*((a0+a1)/(float)SS) + b1[d];
}

// ---------------- logits + softmax + top-2 (one wave per batch) ----------------
__global__ __launch_bounds__(64) void logits_kernel(const float* __restrict__ mv,
                                                    const float* __restrict__ Wg,
                                                    const float* __restrict__ bg,
                                                    float* __restrict__ combine,
                                                    float* __restrict__ probs,
                                                    int* __restrict__ topi,
                                                    float* __restrict__ topw){
    int b = blockIdx.x, lane = threadIdx.x;
    float pl[EE] = {0.f,0.f,0.f,0.f};
    #pragma unroll
    for (int i=0;i<DD/64;++i){
        int d = lane + i*64;
        float m = mv[(size_t)b*DD + d];
        #pragma unroll
        for (int e=0;e<EE;++e) pl[e] += m * Wg[d*EE + e];
    }
    #pragma unroll
    for (int e=0;e<EE;++e){
        #pragma unroll
        for (int o=32;o>0;o>>=1) pl[e] += __shfl_down(pl[e], o);
    }
    if (lane==0){
        float lg[EE];
        for (int e=0;e<EE;++e) lg[e] = pl[e] + bg[e];
        float mx = lg[0];
        for (int e=1;e<EE;++e) mx = fmaxf(mx, lg[e]);
        float p[EE]; float sum=0.f;
        for (int e=0;e<EE;++e){ p[e]=expf(lg[e]-mx); sum+=p[e]; }
        for (int e=0;e<EE;++e) p[e] /= sum;
        int i0=0; for (int e=1;e<EE;++e) if (p[e]>p[i0]) i0=e;
        int i1=-1;
        for (int e=0;e<EE;++e){ if (e==i0) continue; if (i1<0 || p[e]>p[i1]) i1=e; }
        float v0=p[i0], v1=p[i1], rsum=v0+v1;
        float w0=v0/rsum, w1=v1/rsum;
        for (int e=0;e<EE;++e){ probs[b*EE+e]=p[e]; combine[b*EE+e]=0.f; }
        combine[b*EE+i0]=w0; combine[b*EE+i1]=w1;
        topi[b*KKE]=i0; topi[b*KKE+1]=i1;
        topw[b*KKE]=w0; topw[b*KKE+1]=w1;
    }
}

// ---------------- aux loss ----------------
__global__ __launch_bounds__(256) void aux_kernel(const float* __restrict__ combine,
                                                  const float* __restrict__ probs,
                                                  float* __restrict__ aux_out){
    int tid = threadIdx.x; int e = tid>>6, b = tid&63;
    float m = combine[b*EE+e] > 0.f ? 1.f : 0.f;
    float p = probs[b*EE+e];
    #pragma unroll
    for (int o=32;o>0;o>>=1){ m += __shfl_down(m,o); p += __shfl_down(p,o); }
    __shared__ float sh[EE];
    if ((tid&63)==0) sh[e] = (m/(float)BB)*(p/(float)BB);
    __syncthreads();
    if (tid==0) aux_out[0] = (float)EE * (sh[0]+sh[1]+sh[2]+sh[3]);
}

// ---------------- tok GEMM1: htok[be][768][256] = gelu(nTp[b] @ w1tp[e]^T + b1[e]) ----------------
// Epilogue LDS-bounce: coalesced 16B stores (avoid write-allocate refetch of htok).
__global__ __launch_bounds__(256) void tok_gemm1_kernel(
    const __hip_bfloat16* __restrict__ nTp,   // [64][768][256]
    const __hip_bfloat16* __restrict__ w1tp,  // [4][256][256]
    const float* __restrict__ b1,             // [4][196]
    const int* __restrict__ topi,
    __hip_bfloat16* __restrict__ htok)        // [128][768][256]
{
    __shared__ __hip_bfloat16 smem[128*64*2];   // As | Bs; reused as Ht[128][128]
    __hip_bfloat16* As = smem;
    __hip_bfloat16* Bs = smem + 128*64;
    int tid=threadIdx.x, lane=tid&63, w=tid>>6;
    int wm=w>>1, wn=w&1, l15=lane&15, l4=lane>>4;
    int be = blockIdx.z, b = be>>1;
    int e = __builtin_amdgcn_readfirstlane(topi[b*KKE + (be&1)]);
    int m0 = blockIdx.y*128, n0 = blockIdx.x*128;
    const __hip_bfloat16* A  = nTp  + ((size_t)b*DD + m0)*PP;
    const __hip_bfloat16* Bt = w1tp + ((size_t)e*PP + n0)*PP;
    f32x4 acc[4][4];
    #pragma unroll
    for (int mi=0;mi<4;++mi)
        #pragma unroll
        for (int ni=0;ni<4;++ni) acc[mi][ni] = (f32x4){0.f,0.f,0.f,0.f};

    int srow = w*32 + (lane>>3), sc = lane&7;
    int soff = srow*64 + ((sc ^ (srow&7))<<3);
    const __hip_bfloat16* Ap = A + (size_t)srow*PP + sc*8;
    const __hip_bfloat16* Bp = Bt + (size_t)srow*PP + sc*8;
    bf16x8 va[4], vb[4];
    #pragma unroll
    for (int i=0;i<4;++i){
        va[i] = *reinterpret_cast<const bf16x8*>(Ap + (size_t)i*8*PP);
        vb[i] = *reinterpret_cast<const bf16x8*>(Bp + (size_t)i*8*PP);
    }
    for (int k0=0; k0<PP; k0+=64){
        __syncthreads();
        #pragma unroll
        for (int i=0;i<4;++i){
            *reinterpret_cast<bf16x8*>(&As[soff + i*8*64]) = va[i];
            *reinterpret_cast<bf16x8*>(&Bs[soff + i*8*64]) = vb[i];
        }
        __syncthreads();
        if (k0+64 < PP){
            #pragma unroll
            for (int i=0;i<4;++i){
                va[i] = *reinterpret_cast<const bf16x8*>(Ap + (size_t)i*8*PP + (k0+64));
                vb[i] = *reinterpret_cast<const bf16x8*>(Bp + (size_t)i*8*PP + (k0+64));
            }
        }
        #pragma unroll
        for (int kk=0;kk<2;++kk){
            bf16x8 af[4], bfr[4];
            #pragma unroll
            for (int mi=0;mi<4;++mi){
                int r = wm*64 + mi*16 + l15, kc = kk*4 + l4;
                af[mi] = *reinterpret_cast<const bf16x8*>(&As[r*64 + ((kc ^ (r&7))<<3)]);
            }
            #pragma unroll
            for (int ni=0;ni<4;++ni){
                int r = wn*64 + ni*16 + l15, kc = kk*4 + l4;
                bfr[ni] = *reinterpret_cast<const bf16x8*>(&Bs[r*64 + ((kc ^ (r&7))<<3)]);
            }
            #pragma unroll
            for (int mi=0;mi<4;++mi)
                #pragma unroll
                for (int ni=0;ni<4;++ni)
                    acc[mi][ni] = __builtin_amdgcn_mfma_f32_16x16x32_bf16(af[mi], bfr[ni], acc[mi][ni], 0, 0, 0);
        }
    }
    // epilogue: gelu -> Ht in LDS -> coalesced 16B stores
    __syncthreads();
    __hip_bfloat16* Ht = smem;   // [128][128]
    #pragma unroll
    for (int mi=0;mi<4;++mi){
        #pragma unroll
        for (int ni=0;ni<4;++ni){
            int colL = wn*64 + ni*16 + l15;
            int col = n0 + colL;
            float bv = (col < THH) ? b1[e*THH + col] : 0.f;
            #pragma unroll
            for (int r=0;r<4;++r){
                int rowL = wm*64 + mi*16 + l4*4 + r;
                float v = (col < THH) ? gelu_act(acc[mi][ni][r] + bv) : 0.f;
                Ht[rowL*128 + colL] = __float2bfloat16(v);
            }
        }
    }
    __syncthreads();
    for (int i = tid; i < 128*128/8; i += 256){
        int rowL = i >> 4, c8 = i & 15;
        *reinterpret_cast<bf16x8*>(&htok[((size_t)be*DD + m0 + rowL)*PP + n0 + c8*8])
            = *reinterpret_cast<const bf16x8*>(&Ht[rowL*128 + c8*8]);
    }
}

// ---------------- tok GEMM2: x1 = x + sum_k wk*(htok[b,k] @ w2tp[ek]^T + b2[ek]) ----------------
__global__ __launch_bounds__(256) void tok_gemm2_kernel(
    const __hip_bfloat16* __restrict__ htok,  // [128][768][256]
    const __hip_bfloat16* __restrict__ w2tp,  // [4][256][256]
    const float* __restrict__ b2,             // [4][196]
    const int* __restrict__ topi, const float* __restrict__ topw,
    const float* __restrict__ x, float* __restrict__ x1)
{
    __shared__ __hip_bfloat16 As[128*64];
    __shared__ __hip_bfloat16 Bs[128*64];
    int tid=threadIdx.x, lane=tid&63, w=tid>>6;
    int wm=w>>1, wn=w&1, l15=lane&15, l4=lane>>4;
    int b = blockIdx.z;
    int m0 = blockIdx.y*128, n0 = blockIdx.x*128;
    float w0 = topw[b*KKE], w1 = topw[b*KKE+1];
    f32x4 acc[4][4];
    #pragma unroll
    for (int mi=0;mi<4;++mi)
        #pragma unroll
        for (int ni=0;ni<4;++ni) acc[mi][ni] = (f32x4){0.f,0.f,0.f,0.f};

    int srow = w*32 + (lane>>3), sc = lane&7;
    int soff = srow*64 + ((sc ^ (srow&7))<<3);

    for (int pass=0; pass<2; ++pass){
        int e = __builtin_amdgcn_readfirstlane(topi[b*KKE + pass]);
        const __hip_bfloat16* Ap = htok + ((size_t)(b*KKE+pass)*DD + m0 + srow)*PP + sc*8;
        const __hip_bfloat16* Bp = w2tp + ((size_t)e*PP + n0 + srow)*PP + sc*8;
        bf16x8 va[4], vb[4];
        #pragma unroll
        for (int i=0;i<4;++i){
            va[i] = *reinterpret_cast<const bf16x8*>(Ap + (size_t)i*8*PP);
            vb[i] = *reinterpret_cast<const bf16x8*>(Bp + (size_t)i*8*PP);
        }
        for (int k0=0; k0<PP; k0+=64){
            __syncthreads();
            #pragma unroll
            for (int i=0;i<4;++i){
                *reinterpret_cast<bf16x8*>(&As[soff + i*8*64]) = va[i];
                *reinterpret_cast<bf16x8*>(&Bs[soff + i*8*64]) = vb[i];
            }
            __syncthreads();
            if (k0+64 < PP){
                #pragma unroll
                for (int i=0;i<4;++i){
                    va[i] = *reinterpret_cast<const bf16x8*>(Ap + (size_t)i*8*PP + (k0+64));
                    vb[i] = *reinterpret_cast<const bf16x8*>(Bp + (size_t)i*8*PP + (k0+64));
                }
            }
            #pragma unroll
            for (int kk=0;kk<2;++kk){
                bf16x8 af[4], bfr[4];
                #pragma unroll
                for (int mi=0;mi<4;++mi){
                    int r = wm*64 + mi*16 + l15, kc = kk*4 + l4;
                    af[mi] = *reinterpret_cast<const bf16x8*>(&As[r*64 + ((kc ^ (r&7))<<3)]);
                }
                #pragma unroll
                for (int ni=0;ni<4;++ni){
                    int r = wn*64 + ni*16 + l15, kc = kk*4 + l4;
                    bfr[ni] = *reinterpret_cast<const bf16x8*>(&Bs[r*64 + ((kc ^ (r&7))<<3)]);
                }
                #pragma unroll
                for (int mi=0;mi<4;++mi)
                    #pragma unroll
                    for (int ni=0;ni<4;++ni)
                        acc[mi][ni] = __builtin_amdgcn_mfma_f32_16x16x32_bf16(af[mi], bfr[ni], acc[mi][ni], 0, 0, 0);
            }
        }
        if (pass==0){
            float sc0 = w0 / w1;   // softmax top-2 renorm => w1 > 0
            #pragma unroll
            for (int mi=0;mi<4;++mi)
                #pragma unroll
                for (int ni=0;ni<4;++ni)
                    #pragma unroll
                    for (int r=0;r<4;++r) acc[mi][ni][r] *= sc0;
        }
    }
    int e0 = topi[b*KKE], e1 = topi[b*KKE+1];
    #pragma unroll
    for (int mi=0;mi<4;++mi){
        #pragma unroll
        for (int ni=0;ni<4;++ni){
            int col = n0 + wn*64 + ni*16 + l15;   // s index
            if (col < SS){
                float bias = w0*b2[e0*SS+col] + w1*b2[e1*SS+col];
                int rowb = m0 + wm*64 + mi*16 + l4*4;
                size_t idx = ((size_t)b*SS + col)*DD + rowb;
                f32x4 xv = *reinterpret_cast<const f32x4*>(x + idx);
                f32x4 res;
                #pragma unroll
                for (int r=0;r<4;++r) res[r] = xv[r] + w1*acc[mi][ni][r] + bias;
                *reinterpret_cast<f32x4*>(x1 + idx) = res;
            }
        }
    }
}

// ---------------- token mixing fallback (round-7 kernel) ----------------
__global__ __launch_bounds__(256) void tokenmix2_kernel(
    const __hip_bfloat16* __restrict__ nbf, const float* __restrict__ x,
    const float* __restrict__ W1, const float* __restrict__ b1,
    const float* __restrict__ W2, const float* __restrict__ b2,
    const int* __restrict__ topi, const float* __restrict__ topw,
    float* __restrict__ x1)
{
    __shared__ __hip_bfloat16 xs[SS][64];
    __shared__ __hip_bfloat16 Hs[THH][64];
    int b = blockIdx.y, d0 = blockIdx.x*64;
    int tid = threadIdx.x, lane = tid&63, w = tid>>6;
    for (int s = w; s < SS; s += 4)
        xs[s][lane] = nbf[((size_t)b*SS + s)*DD + d0 + lane];
    #pragma unroll
    for (int k=0;k<KKE;++k){
        int e = __builtin_amdgcn_readfirstlane(topi[b*KKE+k]);
        float wgt = topw[b*KKE+k];
        __syncthreads();
        const float* W1e = W1 + (size_t)e*SS*THH;
        for (int hj=0; hj<13; ++hj){
            int hb = w + 16*hj;
            if (hj < 12){
                float a0=b1[e*THH+hb], a1=b1[e*THH+hb+4], a2=b1[e*THH+hb+8], a3=b1[e*THH+hb+12];
                for (int s=0;s<SS;++s){
                    float xv = __bfloat162float(xs[s][lane]);
                    const float* wr = W1e + (size_t)s*THH + hb;
                    a0 += xv*wr[0]; a1 += xv*wr[4]; a2 += xv*wr[8]; a3 += xv*wr[12];
                }
                Hs[hb][lane]    = __float2bfloat16(gelu_act(a0));
                Hs[hb+4][lane]  = __float2bfloat16(gelu_act(a1));
                Hs[hb+8][lane]  = __float2bfloat16(gelu_act(a2));
                Hs[hb+12][lane] = __float2bfloat16(gelu_act(a3));
            } else {
                float a0=b1[e*THH+hb];
                for (int s=0;s<SS;++s)
                    a0 += __bfloat162float(xs[s][lane]) * W1e[(size_t)s*THH + hb];
                Hs[hb][lane] = __float2bfloat16(gelu_act(a0));
            }
        }
        __syncthreads();
        const float* W2e = W2 + (size_t)e*THH*SS;
        for (int sj=0; sj<13; ++sj){
            int sb = w + 16*sj;
            if (sj < 12){
                float o0=b2[e*SS+sb], o1=b2[e*SS+sb+4], o2=b2[e*SS+sb+8], o3=b2[e*SS+sb+12];
                for (int h=0;h<THH;++h){
                    float hv = __bfloat162float(Hs[h][lane]);
                    const float* wr = W2e + (size_t)h*SS + sb;
                    o0 += hv*wr[0]; o1 += hv*wr[4]; o2 += hv*wr[8]; o3 += hv*wr[12];
                }
                float ov[4] = {o0,o1,o2,o3};
                #pragma unroll
                for (int u=0;u<4;++u){
                    size_t idx = ((size_t)b*SS + sb + 4*u)*DD + d0 + lane;
                    float val = wgt*ov[u];
                    if (k==0) x1[idx] = x[idx] + val; else x1[idx] += val;
                }
            } else {
                float o0=b2[e*SS+sb];
                for (int h=0;h<THH;++h)
                    o0 += __bfloat162float(Hs[h][lane]) * W2e[(size_t)h*SS + sb];
                size_t idx = ((size_t)b*SS + sb)*DD + d0 + lane;
                float val = wgt*o0;
                if (k==0) x1[idx] = x[idx] + val; else x1[idx] += val;
            }
        }
    }
}

// ---------------- tiled MFMA GEMM, B^T input (channel MLP) ----------------
// BM=128 fixed, BN template. Reg-prefetch staging + XOR-swizzled LDS + M-grouped
// XCD mapping. EPI==0: LDS-bounce epilogue for coalesced bf16 stores.
template<int KDIM, int EPI, int BN, int NBLK, int MB>
__global__ __launch_bounds__(256) void gemm_bt_kernel(
    const __hip_bfloat16* __restrict__ A,
    const __hip_bfloat16* __restrict__ Bt,
    const float* __restrict__ bias,
    __hip_bfloat16* __restrict__ Hout,
    float* __restrict__ Cio,
    int Ntot)
{
    constexpr int NFR = BN/32;       // n-frags per wave
    constexpr int BCH = BN/32;       // B prefetch chunks per thread
    int id = blockIdx.x;
    int r8 = id & 7, t = id >> 3;
    int qm = t / NBLK, n = t - qm*NBLK;
    int m  = qm*8 + r8;
    if (m >= MB) return;
    int m0 = m*128, n0 = n*BN;

    __shared__ __hip_bfloat16 smem[128*64 + BN*64];  // As | Bs; EPI==0 reuses as Ht[128][BN]
    __hip_bfloat16* As = smem;
    __hip_bfloat16* Bs = smem + 128*64;
    int tid = threadIdx.x, lane = tid&63, w = tid>>6;
    int wm = w>>1, wn = w&1;
    int l15 = lane&15, l4 = lane>>4;
    f32x4 acc[4][NFR];
    #pragma unroll
    for (int mi=0;mi<4;++mi)
        #pragma unroll
        for (int ni=0;ni<NFR;++ni) acc[mi][ni] = (f32x4){0.f,0.f,0.f,0.f};

    int r0 = tid>>3;                 // 0..31
    int sc = tid&7;
    int soff = r0*64 + ((sc ^ (r0&7))<<3);
    const __hip_bfloat16* Ap = A  + (size_t)(m0+r0)*KDIM + sc*8;
    const __hip_bfloat16* Bp = Bt + (size_t)(n0+r0)*KDIM + sc*8;

    bf16x8 va[4], vb[BCH];
    #pragma unroll
    for (int i=0;i<4;++i)
        va[i] = *reinterpret_cast<const bf16x8*>(Ap + (size_t)i*32*KDIM);
    #pragma unroll
    for (int i=0;i<BCH;++i)
        vb[i] = *reinterpret_cast<const bf16x8*>(Bp + (size_t)i*32*KDIM);

    for (int k0=0; k0<KDIM; k0+=64){
        __syncthreads();
        #pragma unroll
        for (int i=0;i<4;++i)
            *reinterpret_cast<bf16x8*>(&As[soff + i*32*64]) = va[i];
        #pragma unroll
        for (int i=0;i<BCH;++i)
            *reinterpret_cast<bf16x8*>(&Bs[soff + i*32*64]) = vb[i];
        __syncthreads();
        if (k0+64 < KDIM){
            #pragma unroll
            for (int i=0;i<4;++i)
                va[i] = *reinterpret_cast<const bf16x8*>(Ap + (size_t)i*32*KDIM + (k0+64));
            #pragma unroll
            for (int i=0;i<BCH;++i)
                vb[i] = *reinterpret_cast<const bf16x8*>(Bp + (size_t)i*32*KDIM + (k0+64));
        }
        #pragma unroll
        for (int kk=0;kk<2;++kk){
            bf16x8 af[4], bfr[NFR];
            #pragma unroll
            for (int mi=0;mi<4;++mi){
                int r = wm*64 + mi*16 + l15;
                int kc = kk*4 + l4;
                af[mi] = *reinterpret_cast<const bf16x8*>(&As[r*64 + ((kc ^ (r&7))<<3)]);
            }
            #pragma unroll
            for (int ni=0;ni<NFR;++ni){
                int r = wn*(BN/2) + ni*16 + l15;
                int kc = kk*4 + l4;
                bfr[ni] = *reinterpret_cast<const bf16x8*>(&Bs[r*64 + ((kc ^ (r&7))<<3)]);
            }
            #pragma unroll
            for (int mi=0;mi<4;++mi)
                #pragma unroll
                for (int ni=0;ni<NFR;++ni)
                    acc[mi][ni] = __builtin_amdgcn_mfma_f32_16x16x32_bf16(af[mi], bfr[ni], acc[mi][ni], 0, 0, 0);
        }
    }
    if (EPI==0){
        // gelu -> Ht in LDS -> coalesced 16B stores (no write-allocate refetch)
        __syncthreads();
        __hip_bfloat16* Ht = smem;   // [128][BN]
        #pragma unroll
        for (int mi=0;mi<4;++mi){
            #pragma unroll
            for (int ni=0;ni<NFR;++ni){
                int colL = wn*(BN/2) + ni*16 + l15;
                float bv = bias[n0 + colL];
                #pragma unroll
                for (int r=0;r<4;++r){
                    int rowL = wm*64 + mi*16 + l4*4 + r;
                    Ht[rowL*BN + colL] = __float2bfloat16(gelu_act(acc[mi][ni][r] + bv));
                }
            }
        }
        __syncthreads();
        for (int i = tid; i < 128*BN/8; i += 256){
            int rowL = i / (BN/8), c8 = i % (BN/8);
            *reinterpret_cast<bf16x8*>(&Hout[(size_t)(m0+rowL)*Ntot + n0 + c8*8])
                = *reinterpret_cast<const bf16x8*>(&Ht[rowL*BN + c8*8]);
        }
    } else {
        #pragma unroll
        for (int mi=0;mi<4;++mi){
            #pragma unroll
            for (int ni=0;ni<NFR;++ni){
                int col = n0 + wn*(BN/2) + ni*16 + l15;
                float bv = bias[col];
                #pragma unroll
                for (int r=0;r<4;++r){
                    int row = m0 + wm*64 + mi*16 + l4*4 + r;
                    Cio[(size_t)row*Ntot + col] += acc[mi][ni][r] + bv;
                }
            }
        }
    }
}

// ---------------- fallback fused MLP (validated round 6) ----------------
__global__ __launch_bounds__(512, 4) void mlp_mfma_kernel(
    const __hip_bfloat16* __restrict__ n2b,
    const __hip_bfloat16* __restrict__ w1t,
    const float* __restrict__ bm1,
    const __hip_bfloat16* __restrict__ w2t,
    const float* __restrict__ bm2,
    float* __restrict__ io)
{
    __shared__ __align__(16) __hip_bfloat16 Ht[32*64];
    int tid = threadIdx.x;
    int wid = tid >> 6, lane = tid & 63;
    int wm = wid >> 2, wn = wid & 3;
    int l15 = lane & 15, l4 = lane >> 4;
    int m0 = blockIdx.x * 32;
    f32x4 acc[12];
    #pragma unroll
    for (int f=0; f<12; ++f) acc[f] = (f32x4){0.f,0.f,0.f,0.f};
    const __hip_bfloat16* aptr = n2b + (size_t)(m0 + wm*16 + l15)*DD + l4*8;
    for (int hc = 0; hc < MHH; hc += 64) {
        f32x4 h = (f32x4){0.f,0.f,0.f,0.f};
        const __hip_bfloat16* bptr = w1t + (size_t)(hc + wn*16 + l15)*DD + l4*8;
        #pragma unroll 4
        for (int ks = 0; ks < DD; ks += 32) {
            bf16x8 a = *reinterpret_cast<const bf16x8*>(aptr + ks);
            bf16x8 bb = *reinterpret_cast<const bf16x8*>(bptr + ks);
            h = __builtin_amdgcn_mfma_f32_16x16x32_bf16(a, bb, h, 0, 0, 0);
        }
        float bv = bm1[hc + wn*16 + l15];
        __syncthreads();
        {
            int col = wn*16 + l15;
            int chunk = col >> 3, inner = col & 7;
            #pragma unroll
            for (int r=0; r<4; ++r) {
                int row = wm*16 + l4*4 + r;
                float v = gelu_act(h[r] + bv);
                Ht[row*64 + ((chunk ^ (row&7))<<3) + inner] = __float2bfloat16(v);
            }
        }
        __syncthreads();
        #pragma unroll
        for (int kk = 0; kk < 2; ++kk) {
            int arow = wm*16 + l15;
            int ach = (kk*32 + l4*8) >> 3;
            bf16x8 aH = *reinterpret_cast<const bf16x8*>(&Ht[arow*64 + ((ach ^ (arow&7))<<3)]);
            const __hip_bfloat16* b2p = w2t + (size_t)(wn*192 + l15)*MHH + hc + kk*32 + l4*8;
            #pragma unroll
            for (int f=0; f<12; ++f) {
                bf16x8 bb = *reinterpret_cast<const bf16x8*>(b2p + (size_t)f*16*MHH);
                acc[f] = __builtin_amdgcn_mfma_f32_16x16x32_bf16(aH, bb, acc[f], 0, 0, 0);
            }
        }
    }
    #pragma unroll
    for (int f=0; f<12; ++f) {
        int col = wn*192 + f*16 + l15;
        float b2v = bm2[col];
        #pragma unroll
        for (int r=0; r<4; ++r) {
            size_t idx = (size_t)(m0 + wm*16 + l4*4 + r)*DD + col;
            io[idx] += acc[f][r] + b2v;
        }
    }
}

extern "C" void kernel_launch(void* const* d_in, const int* in_sizes, int n_in,
                              void* d_out, int out_size, void* d_ws, size_t ws_size,
                              hipStream_t stream) {
    const float* x    = (const float*)d_in[0];
    const float* g1   = (const float*)d_in[1];
    const float* be1  = (const float*)d_in[2];
    const float* Wg   = (const float*)d_in[3];
    const float* bg   = (const float*)d_in[4];
    const float* W1   = (const float*)d_in[5];
    const float* b1e  = (const float*)d_in[6];
    const float* W2   = (const float*)d_in[7];
    const float* b2e  = (const float*)d_in[8];
    const float* g2   = (const float*)d_in[9];
    const float* be2  = (const float*)d_in[10];
    const float* Wm1  = (const float*)d_in[11];
    const float* bm1  = (const float*)d_in[12];
    const float* Wm2  = (const float*)d_in[13];
    const float* bm2  = (const float*)d_in[14];

    float* out = (float*)d_out;
    char* w = (char*)d_ws;

    // ---- ws layout (with aliasing): ----
    const size_t OFF_W1T  = 19267584;                 // nbf: 12544*768*2
    const size_t OFF_W2T  = OFF_W1T + 4718592;        // w1t (mlp)
    const size_t OFF_W1TP = OFF_W2T + 4718592;        // w2t (mlp)   -> 28,704,768
    const size_t OFF_W2TP = OFF_W1TP + (size_t)EE*PP*PP*2;   // +524,288
    const size_t OFF_REG  = OFF_W2TP + (size_t)EE*PP*PP*2;   // 29,753,344
    const size_t NTP_B    = (size_t)BB*DD*PP*2;       // 25,165,824
    const size_t HTOK_B   = (size_t)BB*KKE*DD*PP*2;   // 50,331,648
    const size_t HMLP_B   = (size_t)MM*MHH*2;         // 77,070,336
    const size_t REG_B    = (NTP_B + HTOK_B > HMLP_B) ? (NTP_B + HTOK_B) : HMLP_B;
    const size_t REG_END  = OFF_REG + REG_B;          // 106,823,680
    const size_t NEED     = REG_END + 400000;
    bool bigws = (ws_size >= NEED);

    __hip_bfloat16* nbf  = (__hip_bfloat16*)w;
    __hip_bfloat16* w1t  = (__hip_bfloat16*)(w + OFF_W1T);
    __hip_bfloat16* w2t  = (__hip_bfloat16*)(w + OFF_W2T);
    __hip_bfloat16* w1tp = (__hip_bfloat16*)(w + OFF_W1TP);
    __hip_bfloat16* w2tp = (__hip_bfloat16*)(w + OFF_W2TP);
    __hip_bfloat16* nTp  = (__hip_bfloat16*)(w + OFF_REG);
    __hip_bfloat16* htok = (__hip_bfloat16*)(w + OFF_REG + NTP_B);
    __hip_bfloat16* Hmlp = (__hip_bfloat16*)(w + OFF_REG);

    size_t tail = bigws ? REG_END : OFF_W1TP;
    float* muv     = (float*)(w + tail);
    float* rsigv   = muv + MM;
    float* mv      = rsigv + MM;
    float* combine = mv + (size_t)BB*DD;
    float* probs   = combine + BB*EE;
    float* topw    = probs + BB*EE;
    int*   topi    = (int*)(topw + BB*KKE);

    // 0) one-off weight transposes
    transpose_bf16_kernel<<<dim3(MHH/32, DD/32), 256, 0, stream>>>(Wm1, w1t, DD, MHH);
    transpose_bf16_kernel<<<dim3(DD/32, MHH/32), 256, 0, stream>>>(Wm2, w2t, MHH, DD);
    if (bigws){
        transpose_pad_w_kernel<<<dim3(PP/32, PP/32, EE), 256, 0, stream>>>(W1, w1tp, SS, THH);
        transpose_pad_w_kernel<<<dim3(PP/32, PP/32, EE), 256, 0, stream>>>(W2, w2tp, THH, SS);
    }
    // 1) LN1 -> nbf (bf16) + stats
    ln_bf16_kernel<<<MM, 256, 0, stream>>>(x, g1, be1, nbf, muv, rsigv);
    // 2) router (exact fp32) + aux
    meanvec_kernel<<<dim3(2, BB), 384, 0, stream>>>(x, muv, rsigv, g1, be1, mv);
    logits_kernel<<<BB, 64, 0, stream>>>(mv, Wg, bg, combine, probs, topi, topw);
    aux_kernel<<<1, 256, 0, stream>>>(combine, probs, out + N1);
    // 3) token mixing + residual -> x1 in d_out
    if (bigws){
        transpose_pad_n_kernel<<<dim3(DD/64, PP/64, BB), 256, 0, stream>>>(nbf, nTp);
        tok_gemm1_kernel<<<dim3(PP/128, DD/128, BB*KKE), 256, 0, stream>>>(nTp, w1tp, b1e, topi, htok);
        tok_gemm2_kernel<<<dim3(PP/128, DD/128, BB), 256, 0, stream>>>(htok, w2tp, b2e, topi, topw, x, out);
    } else {
        tokenmix2_kernel<<<dim3(DD/64, BB), 256, 0, stream>>>(nbf, x, W1, b1e, W2, b2e,
                                                              topi, topw, out);
    }
    // 4) LN2(x1) -> nbf
    ln_bf16_kernel<<<MM, 256, 0, stream>>>(out, g2, be2, nbf, muv, rsigv);
    // 5) channel MLP — M-grouped XCD mapping (8 * ceil(98/8)=13 qm-groups)
    if (bigws){
        // GEMM1: 128x128 tile, LDS-bounce epilogue
        gemm_bt_kernel<DD, 0, 128, MHH/128, MM/128><<<8*13*(MHH/128), 256, 0, stream>>>(
            nbf, w1t, bm1, Hmlp, nullptr, MHH);
        // GEMM2: 128x64 tile (best measured config, round 17)
        gemm_bt_kernel<MHH, 1, 64, DD/64, MM/128><<<8*13*(DD/64), 256, 0, stream>>>(
            Hmlp, w2t, bm2, nullptr, out, DD);
    } else {
        mlp_mfma_kernel<<<MM/32, 512, 0, stream>>>(nbf, w1t, bm1, w2t, bm2, out);
    }
}